// Round 7
// baseline (408.312 us; speedup 1.0000x reference)
//
#include <hip/hip_runtime.h>

#define T_SEQ 8192
#define NH 16
#define HD 64
#define DIM 1024
#define ROWS 16384   // 2*8192
#define CHK 256
#define NCHK 32

typedef float f32x4 __attribute__((ext_vector_type(4)));
typedef __bf16 bf16x8 __attribute__((ext_vector_type(8)));
typedef short short8 __attribute__((ext_vector_type(8)));
typedef short short4v __attribute__((ext_vector_type(4)));
typedef unsigned short ushort_t;

__device__ __forceinline__ float bf2f(ushort_t u){ return __uint_as_float(((unsigned)u)<<16); }
__device__ __forceinline__ ushort_t f2bf(float f){
  unsigned u = __float_as_uint(f);
  u += 0x7FFFu + ((u>>16)&1u);
  return (ushort_t)(u>>16);
}
#define BFLO(u) __uint_as_float((u)<<16)
#define BFHI(u) __uint_as_float((u)&0xFFFF0000u)
#define MFMA16(a,b,c) __builtin_amdgcn_mfma_f32_16x16x32_bf16((a),(b),(c),0,0,0)

// ---------------- transpose 5 weights 1024x1024 fp32 -> bf16 (N-major) ----------------
__global__ __launch_bounds__(256) void transpose_all(const float* __restrict__ Wq,
    const float* __restrict__ Wk, const float* __restrict__ Wv,
    const float* __restrict__ Wg, const float* __restrict__ Wo,
    ushort_t* __restrict__ wcat, ushort_t* __restrict__ wot){
  int z = blockIdx.z;
  const float* W = (z==0)?Wq:(z==1)?Wk:(z==2)?Wv:(z==3)?Wg:Wo;
  ushort_t* D = (z<4)? (wcat + (size_t)z*DIM*DIM) : wot;
  __shared__ float tile[64][65];
  int k0 = blockIdx.x*64, n0 = blockIdx.y*64;
  int tid = threadIdx.x;
  #pragma unroll
  for (int it=0; it<16; ++it){
    int idx = tid + it*256;
    int r = idx>>6, c = idx&63;
    tile[r][c] = W[(size_t)(k0+r)*DIM + n0+c];
  }
  __syncthreads();
  #pragma unroll
  for (int it=0; it<16; ++it){
    int idx = tid + it*256;
    int r = idx>>6, c = idx&63;
    D[(size_t)(n0+r)*DIM + k0+c] = f2bf(tile[c][r]);
  }
}

// ---------------- MFMA GEMM (R2-proven, 910 TF): C[M,N] = A[M,K] * Bt[N,K]^T ----------------
template<int OUT_BF16>
__global__ __launch_bounds__(256,2) void gemm_bt(const ushort_t* __restrict__ A,
    const ushort_t* __restrict__ Bt, void* __restrict__ Cv, int M, int N, int K,
    float* __restrict__ ssqp){
  __shared__ __align__(16) ushort_t As[128*64];
  __shared__ __align__(16) ushort_t Bs[128*64];
  int tid = threadIdx.x;
  int lane = tid & 63, wid = tid >> 6;
  int wr = wid >> 1, wc = wid & 1;
  int m0 = blockIdx.x * 128, n0 = blockIdx.y * 128;
  f32x4 acc[4][4] = {};
  int srow = tid >> 3;
  int sg = tid & 7;
  const int nkt = K >> 6;
  for (int kt = 0; kt < nkt; ++kt){
    short8 ra[4], rb[4];
    #pragma unroll
    for (int s = 0; s < 4; ++s){
      int row = s*32 + srow;
      int gl = sg ^ (row & 7);
      ra[s] = *(const short8*)&A[(size_t)(m0 + row)*K + kt*64 + gl*8];
      rb[s] = *(const short8*)&Bt[(size_t)(n0 + row)*K + kt*64 + gl*8];
    }
    __syncthreads();
    #pragma unroll
    for (int s = 0; s < 4; ++s){
      int row = s*32 + srow;
      *(short8*)&As[row*64 + sg*8] = ra[s];
      *(short8*)&Bs[row*64 + sg*8] = rb[s];
    }
    __syncthreads();
    #pragma unroll
    for (int kk = 0; kk < 2; ++kk){
      bf16x8 af[4], bfv[4];
      #pragma unroll
      for (int m = 0; m < 4; ++m){
        int row = wr*64 + m*16 + (lane & 15);
        int g = kk*4 + (lane >> 4);
        af[m] = *(const bf16x8*)&As[row*64 + ((g ^ (row & 7))<<3)];
      }
      #pragma unroll
      for (int n = 0; n < 4; ++n){
        int row = wc*64 + n*16 + (lane & 15);
        int g = kk*4 + (lane >> 4);
        bfv[n] = *(const bf16x8*)&Bs[row*64 + ((g ^ (row & 7))<<3)];
      }
      #pragma unroll
      for (int m = 0; m < 4; ++m)
        #pragma unroll
        for (int n = 0; n < 4; ++n)
          acc[m][n] = MFMA16(af[m], bfv[n], acc[m][n]);
    }
  }
  #pragma unroll
  for (int m = 0; m < 4; ++m){
    int row = m0 + wr*64 + m*16 + (lane>>4)*4;
    #pragma unroll
    for (int n = 0; n < 4; ++n){
      int col = n0 + wc*64 + n*16 + (lane & 15);
      #pragma unroll
      for (int r = 0; r < 4; ++r){
        float v = acc[m][n][r];
        if (OUT_BF16) ((ushort_t*)Cv)[(size_t)(row+r)*N + col] = f2bf(v);
        else          ((float*)Cv)[(size_t)(row+r)*N + col] = v;
      }
    }
  }
  if (OUT_BF16 && blockIdx.y < 24){
    int slot = blockIdx.y*2 + wc;
    #pragma unroll
    for (int m = 0; m < 4; ++m){
      #pragma unroll
      for (int r = 0; r < 4; ++r){
        float s = 0.f;
        #pragma unroll
        for (int n = 0; n < 4; ++n){ float xx = acc[m][n][r]; s += xx*xx; }
        s += __shfl_xor(s,1); s += __shfl_xor(s,2);
        s += __shfl_xor(s,4); s += __shfl_xor(s,8);
        if ((lane & 15) == 0){
          int row = m0 + wr*64 + m*16 + (lane>>4)*4 + r;
          ssqp[(size_t)slot*ROWS + row] = s;
        }
      }
    }
  }
}

// ---------------- combine ssq partials -> inverse rms per (mat,row) ----------------
__global__ __launch_bounds__(256) void rms_combine(const float* __restrict__ ssqp,
                                                   float* __restrict__ rmsb){
  int idx = blockIdx.x*256 + threadIdx.x;    // 3*16384
  int mat = idx >> 14, row = idx & (ROWS-1);
  float s = 0.f;
  #pragma unroll
  for (int k=0;k<16;++k) s += ssqp[(size_t)(mat*16+k)*ROWS + row];
  rmsb[idx] = rsqrtf(s*(1.f/1024.f)+1e-6f);
}

// ---------------- gt = logsigmoid(x @ Wgt)/16  +  fused x->bf16 cast ----------------
__global__ __launch_bounds__(256) void gt_ker(const float* __restrict__ x,
    const float* __restrict__ Wgt, float* __restrict__ gtb, ushort_t* __restrict__ xbf){
  int row = blockIdx.x; int b = row>>13; int t = row & (T_SEQ-1);
  int tid = threadIdx.x; int lane = tid&63; int w = tid>>6;
  __shared__ float xs[1024];
  #pragma unroll
  for (int i=0;i<4;++i) xs[tid+256*i] = x[(size_t)row*DIM + tid+256*i];
  __syncthreads();
  short4v xb4;
  #pragma unroll
  for (int k2=0;k2<4;++k2) xb4[k2] = (short)f2bf(xs[tid*4+k2]);
  *(short4v*)&xbf[(size_t)row*DIM + tid*4] = xb4;
  float a0=0,a1=0,a2=0,a3=0;
  #pragma unroll
  for (int jj=0;jj<16;++jj){
    int j = lane + 64*jj;
    float xv = xs[j];
    const float* wp = &Wgt[(size_t)j*NH + w*4];
    a0 += xv*wp[0]; a1 += xv*wp[1]; a2 += xv*wp[2]; a3 += xv*wp[3];
  }
  #pragma unroll
  for (int off=32; off>=1; off>>=1){
    a0 += __shfl_xor(a0, off); a1 += __shfl_xor(a1, off);
    a2 += __shfl_xor(a2, off); a3 += __shfl_xor(a3, off);
  }
  if (lane==0){
    float za[4] = {a0,a1,a2,a3};
    #pragma unroll
    for (int i=0;i<4;++i){
      float z = za[i];
      float ls = fminf(z,0.f) - log1pf(__expf(-fabsf(z)));
      gtb[((size_t)(b*NH + w*4 + i))*T_SEQ + t] = ls * (1.f/16.f);
    }
  }
}

// ---------------- attention phase 1 (MFMA): kv = (k*rms_k*dec)^T (v*rms_v) ----------------
// 512 threads: staging scatter split 2 threads/row (halves per-thread write chain);
// MFMA on waves 0-3.
__global__ __launch_bounds__(512,2) void attn_p1(const ushort_t* __restrict__ qkvg,
    const float* __restrict__ gtb, const float* __restrict__ rmsb,
    float* __restrict__ Bb, float* __restrict__ kvb){
  __shared__ __align__(16) ushort_t sh2[32768];   // kdt [64][256] | vt [64][256], swizzled
  __shared__ float bcf[256];
  __shared__ float tmp4[4];
  ushort_t* kdt = sh2;
  ushort_t* vt  = sh2 + 16384;
  int bid = blockIdx.x; int n = bid&31; int bh = bid>>5; int b = bh>>4; int h = bh&15;
  int t0 = n*CHK; int tid = threadIdx.x; int lane = tid&63; int w = tid>>6;
  float vscan = 0.f;
  if (tid < 256){
    vscan = gtb[(size_t)bh*T_SEQ + t0 + tid];
    #pragma unroll
    for (int off=1; off<64; off<<=1){ float u = __shfl_up(vscan, off); if (lane>=off) vscan += u; }
    if (lane==63) tmp4[w] = vscan;
  }
  __syncthreads();
  float Bn = tmp4[0]+tmp4[1]+tmp4[2]+tmp4[3];
  if (tid < 256){
    float pre=0;
    #pragma unroll
    for (int i=0;i<4;++i) if (i<w) pre += tmp4[i];
    bcf[tid] = vscan + pre;
  }
  if (tid==0) Bb[bid] = Bn;
  __syncthreads();
  {
    int j = tid>>1, dh = tid&1;
    int grow = b*T_SEQ + t0 + j;
    size_t rowb = (size_t)grow*4096;
    float fk = rmsb[ROWS + grow] * __expf(Bn - bcf[j]);
    float fv = rmsb[2*ROWS + grow];
    #pragma unroll
    for (int q8=0; q8<4; ++q8){
      short8 k8 = *(const short8*)&qkvg[rowb + 1024 + h*HD + dh*32 + q8*8];
      short8 v8 = *(const short8*)&qkvg[rowb + 2048 + h*HD + dh*32 + q8*8];
      #pragma unroll
      for (int kk=0; kk<8; ++kk){
        int d = dh*32 + q8*8 + kk;
        kdt[(d<<8) + (((j>>3)^(d&7))<<3) + (j&7)] = f2bf(bf2f((ushort_t)k8[kk])*fk);
        vt [(d<<8) + (((j>>3)^(d&7))<<3) + (j&7)] = f2bf(bf2f((ushort_t)v8[kk])*fv);
      }
    }
  }
  __syncthreads();
  if (w < 4){
    f32x4 acc[4] = {};
    #pragma unroll
    for (int s=0; s<8; ++s){
      int d = w*16 + (lane&15);
      int jj = s*32 + (lane>>4)*8;
      bf16x8 ka = *(const bf16x8*)&kdt[(d<<8) + (((jj>>3)^(d&7))<<3)];
      #pragma unroll
      for (int et=0; et<4; ++et){
        int e = et*16 + (lane&15);
        bf16x8 vf = *(const bf16x8*)&vt[(e<<8) + (((jj>>3)^(e&7))<<3)];
        acc[et] = MFMA16(ka, vf, acc[et]);
      }
    }
    float* kvp = &kvb[(size_t)bid*4096];
    #pragma unroll
    for (int et=0; et<4; ++et)
      #pragma unroll
      for (int r=0; r<4; ++r)
        kvp[(et*16 + (lane&15))*64 + w*16 + (lane>>4)*4 + r] = acc[et][r];
  }
}

// ---------------- state scan: one thread per (bh, e*64+d), coalesced ----------------
__global__ __launch_bounds__(256) void scan_ker(const float* __restrict__ kvb,
    const float* __restrict__ Bb, ushort_t* __restrict__ Sb){
  int gidx = blockIdx.x*256 + threadIdx.x;
  int bh = gidx >> 12; int f = gidx & 4095;
  float S = 0.f;
  const float* kp = &kvb[(size_t)bh*NCHK*4096 + f];
  ushort_t* sp = &Sb[(size_t)bh*NCHK*4096 + f];
  for (int n=0;n<NCHK;++n){
    sp[(size_t)n*4096] = f2bf(S);
    S = __expf(Bb[bh*NCHK+n])*S + kp[(size_t)n*4096];
  }
}

// ---------------- attention phase 3 (MFMA, load-balanced): wave w owns 16-row
// groups (w, 15-w) -> per-wave causal work is uniform (~9.5 units vs old max 16).
// K/V fragments shared across the group pair. rms factors folded as in R6.
__global__ __launch_bounds__(512,2) void attn_p3(const ushort_t* __restrict__ qkvg,
    const float* __restrict__ gtb, const float* __restrict__ rmsb,
    const ushort_t* __restrict__ Sb, ushort_t* __restrict__ oact){
  __shared__ __align__(16) ushort_t sh[(32768+16384+1024+32+2048)/2];
  ushort_t* vt = sh;                         // [e=64][j=256] swizzled
  ushort_t* ps = sh + 16384;                 // per-wave [32][32] swizzled
  float* bcs = (float*)(sh + 24576);
  float* tmp = (float*)(sh + 25088);
  float* rqs = (float*)(sh + 25104);
  float* rks = (float*)(sh + 25616);
  int bid = blockIdx.x; int n = bid&31; int bh = bid>>5; int b = bh>>4; int h = bh&15;
  int t0 = n*CHK; int tid = threadIdx.x; int lane = tid&63; int w = tid>>6;
  float vscan = 0.f;
  if (tid < 256){
    vscan = gtb[(size_t)bh*T_SEQ + t0 + tid];
    #pragma unroll
    for (int off=1; off<64; off<<=1){ float u = __shfl_up(vscan, off); if (lane>=off) vscan += u; }
    if (lane==63) tmp[w] = vscan;
  }
  __syncthreads();
  if (tid < 256){
    float pre=0;
    #pragma unroll
    for (int i=0;i<4;++i) if (i<w) pre += tmp[i];
    bcs[tid] = vscan + pre;
    int grow = b*T_SEQ + t0 + tid;
    rqs[tid] = rmsb[grow];
    rks[tid] = rmsb[ROWS + grow];
  }
  {
    int j = tid>>1, ehalf = tid&1;
    int grow = b*T_SEQ + t0 + j;
    size_t rowb = (size_t)grow*4096;
    float fv = rmsb[2*ROWS + grow];
    #pragma unroll
    for (int q8=0; q8<4; ++q8){
      short8 v8 = *(const short8*)&qkvg[rowb + 2048 + h*HD + ehalf*32 + q8*8];
      #pragma unroll
      for (int kk=0; kk<8; ++kk){
        int e = ehalf*32 + q8*8 + kk;
        vt[(e<<8) + (((j>>3)^(e&7))<<3) + (j&7)] = f2bf(bf2f((ushort_t)v8[kk])*fv);
      }
    }
  }
  __syncthreads();
  int rb0 = w*16, rb1 = (15-w)*16;           // the wave's two 16-row groups
  size_t chunkbase = (size_t)b*T_SEQ + t0;
  bf16x8 qf[2][2];
  #pragma unroll
  for (int s=0; s<2; ++s){
    qf[0][s] = *(const bf16x8*)&qkvg[(chunkbase + rb0 + (lane&15))*4096
                                      + h*HD + s*32 + (lane>>4)*8];
    qf[1][s] = *(const bf16x8*)&qkvg[(chunkbase + rb1 + (lane&15))*4096
                                      + h*HD + s*32 + (lane>>4)*8];
  }
  f32x4 o_[2][4] = {};
  // cross: O = q @ S^T
  #pragma unroll
  for (int s=0; s<2; ++s)
    #pragma unroll
    for (int et=0; et<4; ++et){
      bf16x8 stf = *(const bf16x8*)&Sb[(size_t)bid*4096 + (et*16 + (lane&15))*64
                                       + s*32 + (lane>>4)*8];
      o_[0][et] = MFMA16(qf[0][s], stf, o_[0][et]);
      o_[1][et] = MFMA16(qf[1][s], stf, o_[1][et]);
    }
  #pragma unroll
  for (int rt=0; rt<2; ++rt)
    #pragma unroll
    for (int rr=0; rr<4; ++rr){
      int ri = (rt? rb1 : rb0) + (lane>>4)*4 + rr;
      float fs = 0.125f*__expf(bcs[ri])*rqs[ri];
      #pragma unroll
      for (int et=0; et<4; ++et) o_[rt][et][rr] *= fs;
    }
  // intra: balanced pair loop
  int h0max = w >> 1;
  int hbmax = (15 - w) >> 1;
  for (int hb=0; hb<=hbmax; ++hb){
    int jbase = hb*32;
    float mb = bcs[(hb>>1)*64];
    bool act0 = (hb <= h0max);
    bool dia0 = (hb == h0max);
    bool dia1 = (hb == hbmax);
    float r8[2][4];
    #pragma unroll
    for (int rr=0; rr<4; ++rr){
      int ri0 = rb0 + (lane>>4)*4 + rr;
      int ri1 = rb1 + (lane>>4)*4 + rr;
      r8[0][rr] = act0 ? 0.125f*__expf(bcs[ri0] - mb)*rqs[ri0] : 0.f;
      r8[1][rr] = 0.125f*__expf(bcs[ri1] - mb)*rqs[ri1];
    }
    float c2[2];
    #pragma unroll
    for (int ct=0; ct<2; ++ct){
      int jc = jbase + ct*16 + (lane&15);
      c2[ct] = __expf(mb - bcs[jc])*rks[jc];
    }
    f32x4 s2[2][2] = {};
    #pragma unroll
    for (int s=0; s<2; ++s)
      #pragma unroll
      for (int ct=0; ct<2; ++ct){
        bf16x8 kf = *(const bf16x8*)&qkvg[(chunkbase + jbase + ct*16 + (lane&15))*4096
                                          + 1024 + h*HD + s*32 + (lane>>4)*8];
        s2[1][ct] = MFMA16(qf[1][s], kf, s2[1][ct]);
        if (act0) s2[0][ct] = MFMA16(qf[0][s], kf, s2[0][ct]);
      }
    // P store (rt1 always; rt0 if active)
    #pragma unroll
    for (int ct=0; ct<2; ++ct)
      #pragma unroll
      for (int rr=0; rr<4; ++rr){
        int pil = (lane>>4)*4 + rr;
        int pj = ct*16 + (lane&15);
        float pv = s2[1][ct][rr] * r8[1][rr] * c2[ct];
        if (dia1 && (jbase + pj) > (rb1 + pil)) pv = 0.f;
        int pi = 16 + pil;
        ps[w*1024 + pi*32 + (((pj>>3) ^ ((pi>>2)&3))<<3) + (pj&7)] = f2bf(pv);
      }
    if (act0){
      #pragma unroll
      for (int ct=0; ct<2; ++ct)
        #pragma unroll
        for (int rr=0; rr<4; ++rr){
          int pil = (lane>>4)*4 + rr;
          int pj = ct*16 + (lane&15);
          float pv = s2[0][ct][rr] * r8[0][rr] * c2[ct];
          if (dia0 && (jbase + pj) > (rb0 + pil)) pv = 0.f;
          ps[w*1024 + pil*32 + (((pj>>3) ^ ((pil>>2)&3))<<3) + (pj&7)] = f2bf(pv);
        }
    }
    // PV
    bf16x8 vf[4];
    #pragma unroll
    for (int et=0; et<4; ++et){
      int e = et*16 + (lane&15);
      int jj = jbase + (lane>>4)*8;
      vf[et] = *(const bf16x8*)&vt[(e<<8) + (((jj>>3) ^ (e&7))<<3)];
    }
    {
      int i1 = 16 + (lane&15);
      bf16x8 pf1 = *(const bf16x8*)&ps[w*1024 + i1*32 + (((lane>>4) ^ ((i1>>2)&3))<<3)];
      #pragma unroll
      for (int et=0; et<4; ++et)
        o_[1][et] = MFMA16(pf1, vf[et], o_[1][et]);
    }
    if (act0){
      int i0 = lane&15;
      bf16x8 pf0 = *(const bf16x8*)&ps[w*1024 + i0*32 + (((lane>>4) ^ ((i0>>2)&3))<<3)];
      #pragma unroll
      for (int et=0; et<4; ++et)
        o_[0][et] = MFMA16(pf0, vf[et], o_[0][et]);
    }
  }
  // epilogue: per-row rmsnorm (d=64), silu(g), coalesced store
  float rms8[2][4];
  #pragma unroll
  for (int rt=0; rt<2; ++rt)
    #pragma unroll
    for (int rr=0; rr<4; ++rr){
      float ssq = 0.f;
      #pragma unroll
      for (int et=0; et<4; ++et){ float xx = o_[rt][et][rr]; ssq += xx*xx; }
      ssq += __shfl_xor(ssq,1); ssq += __shfl_xor(ssq,2);
      ssq += __shfl_xor(ssq,4); ssq += __shfl_xor(ssq,8);
      rms8[rt][rr] = rsqrtf(ssq*(1.f/64.f)+1e-6f);
    }
  #pragma unroll
  for (int eh=0; eh<2; ++eh){
    #pragma unroll
    for (int rt=0; rt<2; ++rt)
      #pragma unroll
      for (int e2=0; e2<2; ++e2){
        int et = eh*2 + e2;
        #pragma unroll
        for (int rr=0; rr<4; ++rr){
          int pi = rt*16 + (lane>>4)*4 + rr;
          int pj = e2*16 + (lane&15);
          ps[w*1024 + pi*32 + (((pj>>3) ^ ((pi>>2)&3))<<3) + (pj&7)] =
            f2bf(o_[rt][et][rr]*rms8[rt][rr]);
        }
      }
    int i2 = lane&31, e16 = (lane>>5)*16;
    int gr0 = e16>>3;
    int f = (i2>>2)&3;
    short8 ov0 = *(const short8*)&ps[w*1024 + i2*32 + ((gr0^f)<<3)];
    short8 ov1 = *(const short8*)&ps[w*1024 + i2*32 + (((gr0+1)^f)<<3)];
    int rowin = (i2 < 16) ? (rb0 + i2) : (rb1 + (i2&15));
    size_t rowg = chunkbase + rowin;
    short8 gv0 = *(const short8*)&qkvg[rowg*4096 + 3072 + h*HD + eh*32 + e16];
    short8 gv1 = *(const short8*)&qkvg[rowg*4096 + 3072 + h*HD + eh*32 + e16 + 8];
    ushort_t outv[16];
    #pragma unroll
    for (int k=0;k<8;++k){
      float gf = bf2f((ushort_t)gv0[k]);
      float sg = gf/(1.f+__expf(-gf));
      outv[k] = f2bf(bf2f((ushort_t)ov0[k])*sg);
    }
    #pragma unroll
    for (int k=0;k<8;++k){
      float gf = bf2f((ushort_t)gv1[k]);
      float sg = gf/(1.f+__expf(-gf));
      outv[8+k] = f2bf(bf2f((ushort_t)ov1[k])*sg);
    }
    ushort_t* op = &oact[rowg*DIM + h*HD + eh*32 + e16];
    *(short8*)&op[0] = *(short8*)&outv[0];
    *(short8*)&op[8] = *(short8*)&outv[8];
  }
}

// ---------------- launch ----------------
extern "C" void kernel_launch(void* const* d_in, const int* in_sizes, int n_in,
                              void* d_out, int out_size, void* d_ws, size_t ws_size,
                              hipStream_t stream){
  const float* x  = (const float*)d_in[0];
  const float* Wq = (const float*)d_in[1];
  const float* Wk = (const float*)d_in[2];
  const float* Wv = (const float*)d_in[3];
  const float* Wg = (const float*)d_in[4];
  const float* Wgt= (const float*)d_in[5];
  const float* Wo = (const float*)d_in[6];
  float* out = (float*)d_out;

  char* p = (char*)d_ws;
  ushort_t* xbf  = (ushort_t*)p; p += (size_t)ROWS*DIM*2;
  ushort_t* wcat = (ushort_t*)p; p += (size_t)4*DIM*DIM*2;
  ushort_t* wot  = (ushort_t*)p; p += (size_t)DIM*DIM*2;
  ushort_t* qkvg = (ushort_t*)p; p += (size_t)ROWS*4096*2;
  float* gtb = (float*)p; p += (size_t)32*T_SEQ*4;
  float* Bb  = (float*)p; p += 1024*4;
  float* kvb = (float*)p; p += (size_t)1024*4096*4;
  ushort_t* Sb = (ushort_t*)p; p += (size_t)1024*4096*2;
  ushort_t* oact = (ushort_t*)p; p += (size_t)ROWS*DIM*2;
  float* ssqp = (float*)p; p += (size_t)48*ROWS*4;
  float* rmsb = (float*)p; p += (size_t)3*ROWS*4;
  if ((size_t)(p - (char*)d_ws) > ws_size) return;

  gt_ker<<<ROWS,256,0,stream>>>(x, Wgt, gtb, xbf);
  transpose_all<<<dim3(16,16,5),256,0,stream>>>(Wq, Wk, Wv, Wg, Wo, wcat, wot);
  gemm_bt<1><<<dim3(ROWS/128, 4096/128), 256, 0, stream>>>(xbf, wcat, qkvg, ROWS, 4096, DIM, ssqp);
  rms_combine<<<(3*ROWS)/256,256,0,stream>>>(ssqp, rmsb);
  attn_p1<<<1024,512,0,stream>>>(qkvg, gtb, rmsb, Bb, kvb);
  scan_ker<<<512,256,0,stream>>>(kvb, Bb, Sb);
  attn_p3<<<1024,512,0,stream>>>(qkvg, gtb, rmsb, Sb, oact);
  gemm_bt<0><<<dim3(ROWS/128, 1024/128), 256, 0, stream>>>(oact, wot, out, ROWS, 1024, DIM, nullptr);
}

// Round 8
// 378.536 us; speedup vs baseline: 1.0787x; 1.0787x over previous
//
#include <hip/hip_runtime.h>

#define T_SEQ 8192
#define NH 16
#define HD 64
#define DIM 1024
#define ROWS 16384   // 2*8192
#define CHK 256
#define NCHK 32

typedef float f32x4 __attribute__((ext_vector_type(4)));
typedef __bf16 bf16x8 __attribute__((ext_vector_type(8)));
typedef short short8 __attribute__((ext_vector_type(8)));
typedef short short4v __attribute__((ext_vector_type(4)));
typedef unsigned short ushort_t;

__device__ __forceinline__ float bf2f(ushort_t u){ return __uint_as_float(((unsigned)u)<<16); }
__device__ __forceinline__ ushort_t f2bf(float f){
  unsigned u = __float_as_uint(f);
  u += 0x7FFFu + ((u>>16)&1u);
  return (ushort_t)(u>>16);
}
#define BFLO(u) __uint_as_float((u)<<16)
#define BFHI(u) __uint_as_float((u)&0xFFFF0000u)
#define MFMA16(a,b,c) __builtin_amdgcn_mfma_f32_16x16x32_bf16((a),(b),(c),0,0,0)

// ---------------- transpose 5 weights 1024x1024 fp32 -> bf16 (N-major) ----------------
__global__ __launch_bounds__(256) void transpose_all(const float* __restrict__ Wq,
    const float* __restrict__ Wk, const float* __restrict__ Wv,
    const float* __restrict__ Wg, const float* __restrict__ Wo,
    ushort_t* __restrict__ wcat, ushort_t* __restrict__ wot){
  int z = blockIdx.z;
  const float* W = (z==0)?Wq:(z==1)?Wk:(z==2)?Wv:(z==3)?Wg:Wo;
  ushort_t* D = (z<4)? (wcat + (size_t)z*DIM*DIM) : wot;
  __shared__ float tile[64][65];
  int k0 = blockIdx.x*64, n0 = blockIdx.y*64;
  int tid = threadIdx.x;
  #pragma unroll
  for (int it=0; it<16; ++it){
    int idx = tid + it*256;
    int r = idx>>6, c = idx&63;
    tile[r][c] = W[(size_t)(k0+r)*DIM + n0+c];
  }
  __syncthreads();
  #pragma unroll
  for (int it=0; it<16; ++it){
    int idx = tid + it*256;
    int r = idx>>6, c = idx&63;
    D[(size_t)(n0+r)*DIM + k0+c] = f2bf(tile[c][r]);
  }
}

// ---------------- MFMA GEMM (R2-proven, 910 TF): C[M,N] = A[M,K] * Bt[N,K]^T ----------------
template<int OUT_BF16>
__global__ __launch_bounds__(256,2) void gemm_bt(const ushort_t* __restrict__ A,
    const ushort_t* __restrict__ Bt, void* __restrict__ Cv, int M, int N, int K,
    float* __restrict__ ssqp){
  __shared__ __align__(16) ushort_t As[128*64];
  __shared__ __align__(16) ushort_t Bs[128*64];
  int tid = threadIdx.x;
  int lane = tid & 63, wid = tid >> 6;
  int wr = wid >> 1, wc = wid & 1;
  int m0 = blockIdx.x * 128, n0 = blockIdx.y * 128;
  f32x4 acc[4][4] = {};
  int srow = tid >> 3;
  int sg = tid & 7;
  const int nkt = K >> 6;
  for (int kt = 0; kt < nkt; ++kt){
    short8 ra[4], rb[4];
    #pragma unroll
    for (int s = 0; s < 4; ++s){
      int row = s*32 + srow;
      int gl = sg ^ (row & 7);
      ra[s] = *(const short8*)&A[(size_t)(m0 + row)*K + kt*64 + gl*8];
      rb[s] = *(const short8*)&Bt[(size_t)(n0 + row)*K + kt*64 + gl*8];
    }
    __syncthreads();
    #pragma unroll
    for (int s = 0; s < 4; ++s){
      int row = s*32 + srow;
      *(short8*)&As[row*64 + sg*8] = ra[s];
      *(short8*)&Bs[row*64 + sg*8] = rb[s];
    }
    __syncthreads();
    #pragma unroll
    for (int kk = 0; kk < 2; ++kk){
      bf16x8 af[4], bfv[4];
      #pragma unroll
      for (int m = 0; m < 4; ++m){
        int row = wr*64 + m*16 + (lane & 15);
        int g = kk*4 + (lane >> 4);
        af[m] = *(const bf16x8*)&As[row*64 + ((g ^ (row & 7))<<3)];
      }
      #pragma unroll
      for (int n = 0; n < 4; ++n){
        int row = wc*64 + n*16 + (lane & 15);
        int g = kk*4 + (lane >> 4);
        bfv[n] = *(const bf16x8*)&Bs[row*64 + ((g ^ (row & 7))<<3)];
      }
      #pragma unroll
      for (int m = 0; m < 4; ++m)
        #pragma unroll
        for (int n = 0; n < 4; ++n)
          acc[m][n] = MFMA16(af[m], bfv[n], acc[m][n]);
    }
  }
  #pragma unroll
  for (int m = 0; m < 4; ++m){
    int row = m0 + wr*64 + m*16 + (lane>>4)*4;
    #pragma unroll
    for (int n = 0; n < 4; ++n){
      int col = n0 + wc*64 + n*16 + (lane & 15);
      #pragma unroll
      for (int r = 0; r < 4; ++r){
        float v = acc[m][n][r];
        if (OUT_BF16) ((ushort_t*)Cv)[(size_t)(row+r)*N + col] = f2bf(v);
        else          ((float*)Cv)[(size_t)(row+r)*N + col] = v;
      }
    }
  }
  if (OUT_BF16 && blockIdx.y < 24){
    int slot = blockIdx.y*2 + wc;
    #pragma unroll
    for (int m = 0; m < 4; ++m){
      #pragma unroll
      for (int r = 0; r < 4; ++r){
        float s = 0.f;
        #pragma unroll
        for (int n = 0; n < 4; ++n){ float xx = acc[m][n][r]; s += xx*xx; }
        s += __shfl_xor(s,1); s += __shfl_xor(s,2);
        s += __shfl_xor(s,4); s += __shfl_xor(s,8);
        if ((lane & 15) == 0){
          int row = m0 + wr*64 + m*16 + (lane>>4)*4 + r;
          ssqp[(size_t)slot*ROWS + row] = s;
        }
      }
    }
  }
}

// ---------------- combine ssq partials -> inverse rms per (mat,row) ----------------
__global__ __launch_bounds__(256) void rms_combine(const float* __restrict__ ssqp,
                                                   float* __restrict__ rmsb){
  int idx = blockIdx.x*256 + threadIdx.x;    // 3*16384
  int mat = idx >> 14, row = idx & (ROWS-1);
  float s = 0.f;
  #pragma unroll
  for (int k=0;k<16;++k) s += ssqp[(size_t)(mat*16+k)*ROWS + row];
  rmsb[idx] = rsqrtf(s*(1.f/1024.f)+1e-6f);
}

// ---------------- gt = logsigmoid(x @ Wgt)/16  +  fused x->bf16 cast ----------------
__global__ __launch_bounds__(256) void gt_ker(const float* __restrict__ x,
    const float* __restrict__ Wgt, float* __restrict__ gtb, ushort_t* __restrict__ xbf){
  int row = blockIdx.x; int b = row>>13; int t = row & (T_SEQ-1);
  int tid = threadIdx.x; int lane = tid&63; int w = tid>>6;
  __shared__ float xs[1024];
  #pragma unroll
  for (int i=0;i<4;++i) xs[tid+256*i] = x[(size_t)row*DIM + tid+256*i];
  __syncthreads();
  short4v xb4;
  #pragma unroll
  for (int k2=0;k2<4;++k2) xb4[k2] = (short)f2bf(xs[tid*4+k2]);
  *(short4v*)&xbf[(size_t)row*DIM + tid*4] = xb4;
  float a0=0,a1=0,a2=0,a3=0;
  #pragma unroll
  for (int jj=0;jj<16;++jj){
    int j = lane + 64*jj;
    float xv = xs[j];
    const float* wp = &Wgt[(size_t)j*NH + w*4];
    a0 += xv*wp[0]; a1 += xv*wp[1]; a2 += xv*wp[2]; a3 += xv*wp[3];
  }
  #pragma unroll
  for (int off=32; off>=1; off>>=1){
    a0 += __shfl_xor(a0, off); a1 += __shfl_xor(a1, off);
    a2 += __shfl_xor(a2, off); a3 += __shfl_xor(a3, off);
  }
  if (lane==0){
    float za[4] = {a0,a1,a2,a3};
    #pragma unroll
    for (int i=0;i<4;++i){
      float z = za[i];
      float ls = fminf(z,0.f) - log1pf(__expf(-fabsf(z)));
      gtb[((size_t)(b*NH + w*4 + i))*T_SEQ + t] = ls * (1.f/16.f);
    }
  }
}

// ---------------- attention phase 1 (MFMA): kv = (k*rms_k*dec)^T (v*rms_v) ----------------
__global__ __launch_bounds__(512,2) void attn_p1(const ushort_t* __restrict__ qkvg,
    const float* __restrict__ gtb, const float* __restrict__ rmsb,
    float* __restrict__ Bb, float* __restrict__ kvb){
  __shared__ __align__(16) ushort_t sh2[32768];   // kdt [64][256] | vt [64][256], swizzled
  __shared__ float bcf[256];
  __shared__ float tmp4[4];
  ushort_t* kdt = sh2;
  ushort_t* vt  = sh2 + 16384;
  int bid = blockIdx.x; int n = bid&31; int bh = bid>>5; int b = bh>>4; int h = bh&15;
  int t0 = n*CHK; int tid = threadIdx.x; int lane = tid&63; int w = tid>>6;
  float vscan = 0.f;
  if (tid < 256){
    vscan = gtb[(size_t)bh*T_SEQ + t0 + tid];
    #pragma unroll
    for (int off=1; off<64; off<<=1){ float u = __shfl_up(vscan, off); if (lane>=off) vscan += u; }
    if (lane==63) tmp4[w] = vscan;
  }
  __syncthreads();
  float Bn = tmp4[0]+tmp4[1]+tmp4[2]+tmp4[3];
  if (tid < 256){
    float pre=0;
    #pragma unroll
    for (int i=0;i<4;++i) if (i<w) pre += tmp4[i];
    bcf[tid] = vscan + pre;
  }
  if (tid==0) Bb[bid] = Bn;
  __syncthreads();
  {
    int j = tid>>1, dh = tid&1;
    int grow = b*T_SEQ + t0 + j;
    size_t rowb = (size_t)grow*4096;
    float fk = rmsb[ROWS + grow] * __expf(Bn - bcf[j]);
    float fv = rmsb[2*ROWS + grow];
    #pragma unroll
    for (int q8=0; q8<4; ++q8){
      short8 k8 = *(const short8*)&qkvg[rowb + 1024 + h*HD + dh*32 + q8*8];
      short8 v8 = *(const short8*)&qkvg[rowb + 2048 + h*HD + dh*32 + q8*8];
      #pragma unroll
      for (int kk=0; kk<8; ++kk){
        int d = dh*32 + q8*8 + kk;
        kdt[(d<<8) + (((j>>3)^(d&7))<<3) + (j&7)] = f2bf(bf2f((ushort_t)k8[kk])*fk);
        vt [(d<<8) + (((j>>3)^(d&7))<<3) + (j&7)] = f2bf(bf2f((ushort_t)v8[kk])*fv);
      }
    }
  }
  __syncthreads();
  if (w < 4){
    f32x4 acc[4] = {};
    #pragma unroll
    for (int s=0; s<8; ++s){
      int d = w*16 + (lane&15);
      int jj = s*32 + (lane>>4)*8;
      bf16x8 ka = *(const bf16x8*)&kdt[(d<<8) + (((jj>>3)^(d&7))<<3)];
      #pragma unroll
      for (int et=0; et<4; ++et){
        int e = et*16 + (lane&15);
        bf16x8 vf = *(const bf16x8*)&vt[(e<<8) + (((jj>>3)^(e&7))<<3)];
        acc[et] = MFMA16(ka, vf, acc[et]);
      }
    }
    float* kvp = &kvb[(size_t)bid*4096];
    #pragma unroll
    for (int et=0; et<4; ++et)
      #pragma unroll
      for (int r=0; r<4; ++r)
        kvp[(et*16 + (lane&15))*64 + w*16 + (lane>>4)*4 + r] = acc[et][r];
  }
}

// ---------------- state scan: one thread per (bh, e*64+d), coalesced ----------------
__global__ __launch_bounds__(256) void scan_ker(const float* __restrict__ kvb,
    const float* __restrict__ Bb, ushort_t* __restrict__ Sb){
  int gidx = blockIdx.x*256 + threadIdx.x;
  int bh = gidx >> 12; int f = gidx & 4095;
  float S = 0.f;
  const float* kp = &kvb[(size_t)bh*NCHK*4096 + f];
  ushort_t* sp = &Sb[(size_t)bh*NCHK*4096 + f];
  for (int n=0;n<NCHK;++n){
    sp[(size_t)n*4096] = f2bf(S);
    S = __expf(Bb[bh*NCHK+n])*S + kp[(size_t)n*4096];
  }
}

// ---------------- attention phase 3 (MFMA, R6 structure + issue-early/prefetch) ----------------
// q/S fragments hoisted to kernel top (latency hides under cumsum+staging+barriers);
// k fragments software-prefetched one hb-iteration ahead. launch_bounds(512,4)
// pins VGPR<=128 so the extra live regs can't halve occupancy.
__global__ __launch_bounds__(512,4) void attn_p3(const ushort_t* __restrict__ qkvg,
    const float* __restrict__ gtb, const float* __restrict__ rmsb,
    const ushort_t* __restrict__ Sb, ushort_t* __restrict__ oact){
  __shared__ __align__(16) ushort_t sh[(32768+16384+1024+32+2048)/2];
  ushort_t* vt = sh;                         // [e=64][j=256] swizzled
  ushort_t* ps = sh + 16384;                 // per-wave [32][32] swizzled
  float* bcs = (float*)(sh + 24576);
  float* tmp = (float*)(sh + 25088);
  float* rqs = (float*)(sh + 25104);
  float* rks = (float*)(sh + 25616);
  int bid = blockIdx.x; int n = bid&31; int bh = bid>>5; int b = bh>>4; int h = bh&15;
  int t0 = n*CHK; int tid = threadIdx.x; int lane = tid&63; int w = tid>>6;
  int wrow = w*32;
  size_t chunkbase = (size_t)b*T_SEQ + t0;
  // ---- hoisted q and S fragment loads (issue-early) ----
  bf16x8 qf[2][2];
  #pragma unroll
  for (int rt=0; rt<2; ++rt)
    #pragma unroll
    for (int s=0; s<2; ++s)
      qf[rt][s] = *(const bf16x8*)&qkvg[(chunkbase + wrow + rt*16 + (lane&15))*4096
                                        + h*HD + s*32 + (lane>>4)*8];
  bf16x8 stf[2][4];
  #pragma unroll
  for (int s=0; s<2; ++s)
    #pragma unroll
    for (int et=0; et<4; ++et)
      stf[s][et] = *(const bf16x8*)&Sb[(size_t)bid*4096 + (et*16 + (lane&15))*64
                                       + s*32 + (lane>>4)*8];
  // ---- cumsum ----
  float vscan = 0.f;
  if (tid < 256){
    vscan = gtb[(size_t)bh*T_SEQ + t0 + tid];
    #pragma unroll
    for (int off=1; off<64; off<<=1){ float u = __shfl_up(vscan, off); if (lane>=off) vscan += u; }
    if (lane==63) tmp[w] = vscan;
  }
  __syncthreads();
  if (tid < 256){
    float pre=0;
    #pragma unroll
    for (int i=0;i<4;++i) if (i<w) pre += tmp[i];
    bcs[tid] = vscan + pre;
    int grow = b*T_SEQ + t0 + tid;
    rqs[tid] = rmsb[grow];
    rks[tid] = rmsb[ROWS + grow];
  }
  // ---- vt staging (all 512 threads) ----
  {
    int j = tid>>1, ehalf = tid&1;
    int grow = b*T_SEQ + t0 + j;
    size_t rowb = (size_t)grow*4096;
    float fv = rmsb[2*ROWS + grow];
    #pragma unroll
    for (int q8=0; q8<4; ++q8){
      short8 v8 = *(const short8*)&qkvg[rowb + 2048 + h*HD + ehalf*32 + q8*8];
      #pragma unroll
      for (int kk=0; kk<8; ++kk){
        int e = ehalf*32 + q8*8 + kk;
        vt[(e<<8) + (((j>>3)^(e&7))<<3) + (j&7)] = f2bf(bf2f((ushort_t)v8[kk])*fv);
      }
    }
  }
  __syncthreads();
  // ---- cross: O = q @ S^T ----
  f32x4 o_[2][4] = {};
  #pragma unroll
  for (int s=0; s<2; ++s)
    #pragma unroll
    for (int et=0; et<4; ++et)
      #pragma unroll
      for (int rt=0; rt<2; ++rt)
        o_[rt][et] = MFMA16(qf[rt][s], stf[s][et], o_[rt][et]);
  #pragma unroll
  for (int rt=0; rt<2; ++rt)
    #pragma unroll
    for (int rr=0; rr<4; ++rr){
      int ri = wrow + rt*16 + (lane>>4)*4 + rr;
      float fs = 0.125f*__expf(bcs[ri])*rqs[ri];
      #pragma unroll
      for (int et=0; et<4; ++et) o_[rt][et][rr] *= fs;
    }
  // ---- intra with k-fragment prefetch ----
  bf16x8 kfc[2][2];
  #pragma unroll
  for (int s=0; s<2; ++s)
    #pragma unroll
    for (int ct=0; ct<2; ++ct)
      kfc[s][ct] = *(const bf16x8*)&qkvg[(chunkbase + ct*16 + (lane&15))*4096
                                         + 1024 + h*HD + s*32 + (lane>>4)*8];
  for (int hb=0; hb<=w; ++hb){
    int jb = hb>>1, ch = hb&1;
    int jbase = jb*64 + ch*32;
    bf16x8 kfn[2][2];
    if (hb < w){
      int jb2 = ((hb+1)>>1)*64 + ((hb+1)&1)*32;
      #pragma unroll
      for (int s=0; s<2; ++s)
        #pragma unroll
        for (int ct=0; ct<2; ++ct)
          kfn[s][ct] = *(const bf16x8*)&qkvg[(chunkbase + jb2 + ct*16 + (lane&15))*4096
                                             + 1024 + h*HD + s*32 + (lane>>4)*8];
    }
    float mb = bcs[jb*64];
    float r8[2][4];
    #pragma unroll
    for (int rt=0; rt<2; ++rt)
      #pragma unroll
      for (int rr=0; rr<4; ++rr){
        int ri = wrow + rt*16 + (lane>>4)*4 + rr;
        r8[rt][rr] = 0.125f*__expf(bcs[ri] - mb)*rqs[ri];
      }
    float c2[2];
    #pragma unroll
    for (int ct=0; ct<2; ++ct){
      int jc = jbase + ct*16 + (lane&15);
      c2[ct] = __expf(mb - bcs[jc])*rks[jc];
    }
    f32x4 s2[2][2] = {};
    #pragma unroll
    for (int s=0; s<2; ++s)
      #pragma unroll
      for (int ct=0; ct<2; ++ct)
        #pragma unroll
        for (int rt=0; rt<2; ++rt)
          s2[rt][ct] = MFMA16(qf[rt][s], kfc[s][ct], s2[rt][ct]);
    bool dia = (hb == w);
    #pragma unroll
    for (int rt=0; rt<2; ++rt)
      #pragma unroll
      for (int ct=0; ct<2; ++ct)
        #pragma unroll
        for (int rr=0; rr<4; ++rr){
          int pi = rt*16 + (lane>>4)*4 + rr;
          int pj = ct*16 + (lane&15);
          float pv = s2[rt][ct][rr] * r8[rt][rr] * c2[ct];
          if (dia && (jbase + pj) > (wrow + pi)) pv = 0.f;
          ps[w*1024 + pi*32 + (((pj>>3) ^ ((pi>>2)&3))<<3) + (pj&7)] = f2bf(pv);
        }
    bf16x8 vf[4];
    #pragma unroll
    for (int et=0; et<4; ++et){
      int e = et*16 + (lane&15);
      int jj = jbase + (lane>>4)*8;
      vf[et] = *(const bf16x8*)&vt[(e<<8) + (((jj>>3) ^ (e&7))<<3)];
    }
    bf16x8 pf[2];
    #pragma unroll
    for (int rt=0; rt<2; ++rt){
      int i = rt*16 + (lane&15);
      pf[rt] = *(const bf16x8*)&ps[w*1024 + i*32 + (((lane>>4) ^ ((i>>2)&3))<<3)];
    }
    #pragma unroll
    for (int rt=0; rt<2; ++rt)
      #pragma unroll
      for (int et=0; et<4; ++et)
        o_[rt][et] = MFMA16(pf[rt], vf[et], o_[rt][et]);
    if (hb < w){
      #pragma unroll
      for (int s=0; s<2; ++s)
        #pragma unroll
        for (int ct=0; ct<2; ++ct)
          kfc[s][ct] = kfn[s][ct];
    }
  }
  // ---- epilogue: per-row rmsnorm (d=64), silu(g), coalesced store ----
  float rms8[2][4];
  #pragma unroll
  for (int rt=0; rt<2; ++rt)
    #pragma unroll
    for (int rr=0; rr<4; ++rr){
      float ssq = 0.f;
      #pragma unroll
      for (int et=0; et<4; ++et){ float xx = o_[rt][et][rr]; ssq += xx*xx; }
      ssq += __shfl_xor(ssq,1); ssq += __shfl_xor(ssq,2);
      ssq += __shfl_xor(ssq,4); ssq += __shfl_xor(ssq,8);
      rms8[rt][rr] = rsqrtf(ssq*(1.f/64.f)+1e-6f);
    }
  #pragma unroll
  for (int eh=0; eh<2; ++eh){
    #pragma unroll
    for (int rt=0; rt<2; ++rt)
      #pragma unroll
      for (int e2=0; e2<2; ++e2){
        int et = eh*2 + e2;
        #pragma unroll
        for (int rr=0; rr<4; ++rr){
          int pi = rt*16 + (lane>>4)*4 + rr;
          int pj = e2*16 + (lane&15);
          ps[w*1024 + pi*32 + (((pj>>3) ^ ((pi>>2)&3))<<3) + (pj&7)] =
            f2bf(o_[rt][et][rr]*rms8[rt][rr]);
        }
      }
    int i2 = lane&31, e16 = (lane>>5)*16;
    int gr0 = e16>>3;
    int f = (i2>>2)&3;
    short8 ov0 = *(const short8*)&ps[w*1024 + i2*32 + ((gr0^f)<<3)];
    short8 ov1 = *(const short8*)&ps[w*1024 + i2*32 + (((gr0+1)^f)<<3)];
    size_t rowg = chunkbase + wrow + i2;
    short8 gv0 = *(const short8*)&qkvg[rowg*4096 + 3072 + h*HD + eh*32 + e16];
    short8 gv1 = *(const short8*)&qkvg[rowg*4096 + 3072 + h*HD + eh*32 + e16 + 8];
    ushort_t outv[16];
    #pragma unroll
    for (int k=0;k<8;++k){
      float gf = bf2f((ushort_t)gv0[k]);
      float sg = gf/(1.f+__expf(-gf));
      outv[k] = f2bf(bf2f((ushort_t)ov0[k])*sg);
    }
    #pragma unroll
    for (int k=0;k<8;++k){
      float gf = bf2f((ushort_t)gv1[k]);
      float sg = gf/(1.f+__expf(-gf));
      outv[8+k] = f2bf(bf2f((ushort_t)ov1[k])*sg);
    }
    ushort_t* op = &oact[rowg*DIM + h*HD + eh*32 + e16];
    *(short8*)&op[0] = *(short8*)&outv[0];
    *(short8*)&op[8] = *(short8*)&outv[8];
  }
}

// ---------------- launch ----------------
extern "C" void kernel_launch(void* const* d_in, const int* in_sizes, int n_in,
                              void* d_out, int out_size, void* d_ws, size_t ws_size,
                              hipStream_t stream){
  const float* x  = (const float*)d_in[0];
  const float* Wq = (const float*)d_in[1];
  const float* Wk = (const float*)d_in[2];
  const float* Wv = (const float*)d_in[3];
  const float* Wg = (const float*)d_in[4];
  const float* Wgt= (const float*)d_in[5];
  const float* Wo = (const float*)d_in[6];
  float* out = (float*)d_out;

  char* p = (char*)d_ws;
  ushort_t* xbf  = (ushort_t*)p; p += (size_t)ROWS*DIM*2;
  ushort_t* wcat = (ushort_t*)p; p += (size_t)4*DIM*DIM*2;
  ushort_t* wot  = (ushort_t*)p; p += (size_t)DIM*DIM*2;
  ushort_t* qkvg = (ushort_t*)p; p += (size_t)ROWS*4096*2;
  float* gtb = (float*)p; p += (size_t)32*T_SEQ*4;
  float* Bb  = (float*)p; p += 1024*4;
  float* kvb = (float*)p; p += (size_t)1024*4096*4;
  ushort_t* Sb = (ushort_t*)p; p += (size_t)1024*4096*2;
  ushort_t* oact = (ushort_t*)p; p += (size_t)ROWS*DIM*2;
  float* ssqp = (float*)p; p += (size_t)48*ROWS*4;
  float* rmsb = (float*)p; p += (size_t)3*ROWS*4;
  if ((size_t)(p - (char*)d_ws) > ws_size) return;

  gt_ker<<<ROWS,256,0,stream>>>(x, Wgt, gtb, xbf);
  transpose_all<<<dim3(16,16,5),256,0,stream>>>(Wq, Wk, Wv, Wg, Wo, wcat, wot);
  gemm_bt<1><<<dim3(ROWS/128, 4096/128), 256, 0, stream>>>(xbf, wcat, qkvg, ROWS, 4096, DIM, ssqp);
  rms_combine<<<(3*ROWS)/256,256,0,stream>>>(ssqp, rmsb);
  attn_p1<<<1024,512,0,stream>>>(qkvg, gtb, rmsb, Bb, kvb);
  scan_ker<<<512,256,0,stream>>>(kvb, Bb, Sb);
  attn_p3<<<1024,512,0,stream>>>(qkvg, gtb, rmsb, Sb, oact);
  gemm_bt<0><<<dim3(ROWS/128, 1024/128), 256, 0, stream>>>(oact, wot, out, ROWS, 1024, DIM, nullptr);
}

// Round 9
// 377.263 us; speedup vs baseline: 1.0823x; 1.0034x over previous
//
#include <hip/hip_runtime.h>

#define T_SEQ 8192
#define NH 16
#define HD 64
#define DIM 1024
#define ROWS 16384   // 2*8192
#define CHK 256
#define NCHK 32

typedef float f32x4 __attribute__((ext_vector_type(4)));
typedef __bf16 bf16x8 __attribute__((ext_vector_type(8)));
typedef short short8 __attribute__((ext_vector_type(8)));
typedef short short4v __attribute__((ext_vector_type(4)));
typedef unsigned short ushort_t;

__device__ __forceinline__ float bf2f(ushort_t u){ return __uint_as_float(((unsigned)u)<<16); }
__device__ __forceinline__ ushort_t f2bf(float f){
  unsigned u = __float_as_uint(f);
  u += 0x7FFFu + ((u>>16)&1u);
  return (ushort_t)(u>>16);
}
#define BFLO(u) __uint_as_float((u)<<16)
#define BFHI(u) __uint_as_float((u)&0xFFFF0000u)
#define MFMA16(a,b,c) __builtin_amdgcn_mfma_f32_16x16x32_bf16((a),(b),(c),0,0,0)

// ---------------- transpose 5 weights 1024x1024 fp32 -> bf16 (N-major) ----------------
__global__ __launch_bounds__(256) void transpose_all(const float* __restrict__ Wq,
    const float* __restrict__ Wk, const float* __restrict__ Wv,
    const float* __restrict__ Wg, const float* __restrict__ Wo,
    ushort_t* __restrict__ wcat, ushort_t* __restrict__ wot){
  int z = blockIdx.z;
  const float* W = (z==0)?Wq:(z==1)?Wk:(z==2)?Wv:(z==3)?Wg:Wo;
  ushort_t* D = (z<4)? (wcat + (size_t)z*DIM*DIM) : wot;
  __shared__ float tile[64][65];
  int k0 = blockIdx.x*64, n0 = blockIdx.y*64;
  int tid = threadIdx.x;
  #pragma unroll
  for (int it=0; it<16; ++it){
    int idx = tid + it*256;
    int r = idx>>6, c = idx&63;
    tile[r][c] = W[(size_t)(k0+r)*DIM + n0+c];
  }
  __syncthreads();
  #pragma unroll
  for (int it=0; it<16; ++it){
    int idx = tid + it*256;
    int r = idx>>6, c = idx&63;
    D[(size_t)(n0+r)*DIM + k0+c] = f2bf(tile[c][r]);
  }
}

// ---------------- MFMA GEMM (R2-proven, 910 TF): C[M,N] = A[M,K] * Bt[N,K]^T ----------------
template<int OUT_BF16>
__global__ __launch_bounds__(256,2) void gemm_bt(const ushort_t* __restrict__ A,
    const ushort_t* __restrict__ Bt, void* __restrict__ Cv, int M, int N, int K,
    float* __restrict__ ssqp){
  __shared__ __align__(16) ushort_t As[128*64];
  __shared__ __align__(16) ushort_t Bs[128*64];
  int tid = threadIdx.x;
  int lane = tid & 63, wid = tid >> 6;
  int wr = wid >> 1, wc = wid & 1;
  int m0 = blockIdx.x * 128, n0 = blockIdx.y * 128;
  f32x4 acc[4][4] = {};
  int srow = tid >> 3;
  int sg = tid & 7;
  const int nkt = K >> 6;
  for (int kt = 0; kt < nkt; ++kt){
    short8 ra[4], rb[4];
    #pragma unroll
    for (int s = 0; s < 4; ++s){
      int row = s*32 + srow;
      int gl = sg ^ (row & 7);
      ra[s] = *(const short8*)&A[(size_t)(m0 + row)*K + kt*64 + gl*8];
      rb[s] = *(const short8*)&Bt[(size_t)(n0 + row)*K + kt*64 + gl*8];
    }
    __syncthreads();
    #pragma unroll
    for (int s = 0; s < 4; ++s){
      int row = s*32 + srow;
      *(short8*)&As[row*64 + sg*8] = ra[s];
      *(short8*)&Bs[row*64 + sg*8] = rb[s];
    }
    __syncthreads();
    #pragma unroll
    for (int kk = 0; kk < 2; ++kk){
      bf16x8 af[4], bfv[4];
      #pragma unroll
      for (int m = 0; m < 4; ++m){
        int row = wr*64 + m*16 + (lane & 15);
        int g = kk*4 + (lane >> 4);
        af[m] = *(const bf16x8*)&As[row*64 + ((g ^ (row & 7))<<3)];
      }
      #pragma unroll
      for (int n = 0; n < 4; ++n){
        int row = wc*64 + n*16 + (lane & 15);
        int g = kk*4 + (lane >> 4);
        bfv[n] = *(const bf16x8*)&Bs[row*64 + ((g ^ (row & 7))<<3)];
      }
      #pragma unroll
      for (int m = 0; m < 4; ++m)
        #pragma unroll
        for (int n = 0; n < 4; ++n)
          acc[m][n] = MFMA16(af[m], bfv[n], acc[m][n]);
    }
  }
  #pragma unroll
  for (int m = 0; m < 4; ++m){
    int row = m0 + wr*64 + m*16 + (lane>>4)*4;
    #pragma unroll
    for (int n = 0; n < 4; ++n){
      int col = n0 + wc*64 + n*16 + (lane & 15);
      #pragma unroll
      for (int r = 0; r < 4; ++r){
        float v = acc[m][n][r];
        if (OUT_BF16) ((ushort_t*)Cv)[(size_t)(row+r)*N + col] = f2bf(v);
        else          ((float*)Cv)[(size_t)(row+r)*N + col] = v;
      }
    }
  }
  if (OUT_BF16 && blockIdx.y < 24){
    int slot = blockIdx.y*2 + wc;
    #pragma unroll
    for (int m = 0; m < 4; ++m){
      #pragma unroll
      for (int r = 0; r < 4; ++r){
        float s = 0.f;
        #pragma unroll
        for (int n = 0; n < 4; ++n){ float xx = acc[m][n][r]; s += xx*xx; }
        s += __shfl_xor(s,1); s += __shfl_xor(s,2);
        s += __shfl_xor(s,4); s += __shfl_xor(s,8);
        if ((lane & 15) == 0){
          int row = m0 + wr*64 + m*16 + (lane>>4)*4 + r;
          ssqp[(size_t)slot*ROWS + row] = s;
        }
      }
    }
  }
}

// ---------------- combine ssq partials -> inverse rms per (mat,row) ----------------
__global__ __launch_bounds__(256) void rms_combine(const float* __restrict__ ssqp,
                                                   float* __restrict__ rmsb){
  int idx = blockIdx.x*256 + threadIdx.x;    // 3*16384
  int mat = idx >> 14, row = idx & (ROWS-1);
  float s = 0.f;
  #pragma unroll
  for (int k=0;k<16;++k) s += ssqp[(size_t)(mat*16+k)*ROWS + row];
  rmsb[idx] = rsqrtf(s*(1.f/1024.f)+1e-6f);
}

// ---------------- gt = logsigmoid(x @ Wgt)/16  +  fused x->bf16 cast ----------------
__global__ __launch_bounds__(256) void gt_ker(const float* __restrict__ x,
    const float* __restrict__ Wgt, float* __restrict__ gtb, ushort_t* __restrict__ xbf){
  int row = blockIdx.x; int b = row>>13; int t = row & (T_SEQ-1);
  int tid = threadIdx.x; int lane = tid&63; int w = tid>>6;
  __shared__ float xs[1024];
  #pragma unroll
  for (int i=0;i<4;++i) xs[tid+256*i] = x[(size_t)row*DIM + tid+256*i];
  __syncthreads();
  short4v xb4;
  #pragma unroll
  for (int k2=0;k2<4;++k2) xb4[k2] = (short)f2bf(xs[tid*4+k2]);
  *(short4v*)&xbf[(size_t)row*DIM + tid*4] = xb4;
  float a0=0,a1=0,a2=0,a3=0;
  #pragma unroll
  for (int jj=0;jj<16;++jj){
    int j = lane + 64*jj;
    float xv = xs[j];
    const float* wp = &Wgt[(size_t)j*NH + w*4];
    a0 += xv*wp[0]; a1 += xv*wp[1]; a2 += xv*wp[2]; a3 += xv*wp[3];
  }
  #pragma unroll
  for (int off=32; off>=1; off>>=1){
    a0 += __shfl_xor(a0, off); a1 += __shfl_xor(a1, off);
    a2 += __shfl_xor(a2, off); a3 += __shfl_xor(a3, off);
  }
  if (lane==0){
    float za[4] = {a0,a1,a2,a3};
    #pragma unroll
    for (int i=0;i<4;++i){
      float z = za[i];
      float ls = fminf(z,0.f) - log1pf(__expf(-fabsf(z)));
      gtb[((size_t)(b*NH + w*4 + i))*T_SEQ + t] = ls * (1.f/16.f);
    }
  }
}

// ---------------- attention phase 1 (MFMA): kv = (k*rms_k*dec)^T (v*rms_v), kv bf16 [e][d] ----------------
__global__ __launch_bounds__(512,2) void attn_p1(const ushort_t* __restrict__ qkvg,
    const float* __restrict__ gtb, const float* __restrict__ rmsb,
    float* __restrict__ Bb, ushort_t* __restrict__ kvb){
  __shared__ __align__(16) ushort_t sh2[32768];   // kdt [64][256] | vt [64][256], swizzled
  __shared__ float bcf[256];
  __shared__ float tmp4[4];
  ushort_t* kdt = sh2;
  ushort_t* vt  = sh2 + 16384;
  int bid = blockIdx.x; int n = bid&31; int bh = bid>>5; int b = bh>>4; int h = bh&15;
  int t0 = n*CHK; int tid = threadIdx.x; int lane = tid&63; int w = tid>>6;
  float vscan = 0.f;
  if (tid < 256){
    vscan = gtb[(size_t)bh*T_SEQ + t0 + tid];
    #pragma unroll
    for (int off=1; off<64; off<<=1){ float u = __shfl_up(vscan, off); if (lane>=off) vscan += u; }
    if (lane==63) tmp4[w] = vscan;
  }
  __syncthreads();
  float Bn = tmp4[0]+tmp4[1]+tmp4[2]+tmp4[3];
  if (tid < 256){
    float pre=0;
    #pragma unroll
    for (int i=0;i<4;++i) if (i<w) pre += tmp4[i];
    bcf[tid] = vscan + pre;
  }
  if (tid==0) Bb[bid] = Bn;
  __syncthreads();
  {
    int j = tid>>1, dh = tid&1;
    int grow = b*T_SEQ + t0 + j;
    size_t rowb = (size_t)grow*4096;
    float fk = rmsb[ROWS + grow] * __expf(Bn - bcf[j]);
    float fv = rmsb[2*ROWS + grow];
    #pragma unroll
    for (int q8=0; q8<4; ++q8){
      short8 k8 = *(const short8*)&qkvg[rowb + 1024 + h*HD + dh*32 + q8*8];
      short8 v8 = *(const short8*)&qkvg[rowb + 2048 + h*HD + dh*32 + q8*8];
      #pragma unroll
      for (int kk=0; kk<8; ++kk){
        int d = dh*32 + q8*8 + kk;
        kdt[(d<<8) + (((j>>3)^(d&7))<<3) + (j&7)] = f2bf(bf2f((ushort_t)k8[kk])*fk);
        vt [(d<<8) + (((j>>3)^(d&7))<<3) + (j&7)] = f2bf(bf2f((ushort_t)v8[kk])*fv);
      }
    }
  }
  __syncthreads();
  if (w < 4){
    f32x4 acc[4] = {};
    #pragma unroll
    for (int s=0; s<8; ++s){
      int d = w*16 + (lane&15);
      int jj = s*32 + (lane>>4)*8;
      bf16x8 ka = *(const bf16x8*)&kdt[(d<<8) + (((jj>>3)^(d&7))<<3)];
      #pragma unroll
      for (int et=0; et<4; ++et){
        int e = et*16 + (lane&15);
        bf16x8 vf = *(const bf16x8*)&vt[(e<<8) + (((jj>>3)^(e&7))<<3)];
        acc[et] = MFMA16(ka, vf, acc[et]);
      }
    }
    ushort_t* kvp = &kvb[(size_t)bid*4096];
    #pragma unroll
    for (int et=0; et<4; ++et)
      #pragma unroll
      for (int r=0; r<4; ++r)
        kvp[(et*16 + (lane&15))*64 + w*16 + (lane>>4)*4 + r] = f2bf(acc[et][r]);
  }
}

// ---------------- state scan: one thread per (bh, e*64+d), coalesced, bf16 kv ----------------
__global__ __launch_bounds__(256) void scan_ker(const ushort_t* __restrict__ kvb,
    const float* __restrict__ Bb, ushort_t* __restrict__ Sb){
  int gidx = blockIdx.x*256 + threadIdx.x;
  int bh = gidx >> 12; int f = gidx & 4095;
  float S = 0.f;
  const ushort_t* kp = &kvb[(size_t)bh*NCHK*4096 + f];
  ushort_t* sp = &Sb[(size_t)bh*NCHK*4096 + f];
  for (int n=0;n<NCHK;++n){
    sp[(size_t)n*4096] = f2bf(S);
    S = __expf(Bb[bh*NCHK+n])*S + bf2f(kp[(size_t)n*4096]);
  }
}

// ---------------- attention phase 3 (MFMA, R6 structure + hoisted q only) ----------------
// qf hoisted (16 VGPR, issue-early); stf/kf streamed from global (L2/L3-hot).
// launch_bounds(512,2): allocator free -> no spills (R8's (512,4) forced VGPR<=128 -> scratch).
__global__ __launch_bounds__(512,2) void attn_p3(const ushort_t* __restrict__ qkvg,
    const float* __restrict__ gtb, const float* __restrict__ rmsb,
    const ushort_t* __restrict__ Sb, ushort_t* __restrict__ oact){
  __shared__ __align__(16) ushort_t sh[(32768+16384+1024+32+2048)/2];
  ushort_t* vt = sh;                         // [e=64][j=256] swizzled
  ushort_t* ps = sh + 16384;                 // per-wave [32][32] swizzled
  float* bcs = (float*)(sh + 24576);
  float* tmp = (float*)(sh + 25088);
  float* rqs = (float*)(sh + 25104);
  float* rks = (float*)(sh + 25616);
  int bid = blockIdx.x; int n = bid&31; int bh = bid>>5; int b = bh>>4; int h = bh&15;
  int t0 = n*CHK; int tid = threadIdx.x; int lane = tid&63; int w = tid>>6;
  int wrow = w*32;
  size_t chunkbase = (size_t)b*T_SEQ + t0;
  // hoisted q fragment loads (issue-early; latency hides under cumsum+staging)
  bf16x8 qf[2][2];
  #pragma unroll
  for (int rt=0; rt<2; ++rt)
    #pragma unroll
    for (int s=0; s<2; ++s)
      qf[rt][s] = *(const bf16x8*)&qkvg[(chunkbase + wrow + rt*16 + (lane&15))*4096
                                        + h*HD + s*32 + (lane>>4)*8];
  // cumsum
  float vscan = 0.f;
  if (tid < 256){
    vscan = gtb[(size_t)bh*T_SEQ + t0 + tid];
    #pragma unroll
    for (int off=1; off<64; off<<=1){ float u = __shfl_up(vscan, off); if (lane>=off) vscan += u; }
    if (lane==63) tmp[w] = vscan;
  }
  __syncthreads();
  if (tid < 256){
    float pre=0;
    #pragma unroll
    for (int i=0;i<4;++i) if (i<w) pre += tmp[i];
    bcs[tid] = vscan + pre;
    int grow = b*T_SEQ + t0 + tid;
    rqs[tid] = rmsb[grow];
    rks[tid] = rmsb[ROWS + grow];
  }
  // vt staging (all 512 threads)
  {
    int j = tid>>1, ehalf = tid&1;
    int grow = b*T_SEQ + t0 + j;
    size_t rowb = (size_t)grow*4096;
    float fv = rmsb[2*ROWS + grow];
    #pragma unroll
    for (int q8=0; q8<4; ++q8){
      short8 v8 = *(const short8*)&qkvg[rowb + 2048 + h*HD + ehalf*32 + q8*8];
      #pragma unroll
      for (int kk=0; kk<8; ++kk){
        int e = ehalf*32 + q8*8 + kk;
        vt[(e<<8) + (((j>>3)^(e&7))<<3) + (j&7)] = f2bf(bf2f((ushort_t)v8[kk])*fv);
      }
    }
  }
  __syncthreads();
  // cross: O = q @ S^T (stf streamed)
  f32x4 o_[2][4] = {};
  #pragma unroll
  for (int s=0; s<2; ++s)
    #pragma unroll
    for (int et=0; et<4; ++et){
      bf16x8 stf = *(const bf16x8*)&Sb[(size_t)bid*4096 + (et*16 + (lane&15))*64
                                       + s*32 + (lane>>4)*8];
      #pragma unroll
      for (int rt=0; rt<2; ++rt)
        o_[rt][et] = MFMA16(qf[rt][s], stf, o_[rt][et]);
    }
  #pragma unroll
  for (int rt=0; rt<2; ++rt)
    #pragma unroll
    for (int rr=0; rr<4; ++rr){
      int ri = wrow + rt*16 + (lane>>4)*4 + rr;
      float fs = 0.125f*__expf(bcs[ri])*rqs[ri];
      #pragma unroll
      for (int et=0; et<4; ++et) o_[rt][et][rr] *= fs;
    }
  // intra (kf streamed)
  for (int hb=0; hb<=w; ++hb){
    int jb = hb>>1, ch = hb&1;
    int jbase = jb*64 + ch*32;
    float mb = bcs[jb*64];
    float r8[2][4];
    #pragma unroll
    for (int rt=0; rt<2; ++rt)
      #pragma unroll
      for (int rr=0; rr<4; ++rr){
        int ri = wrow + rt*16 + (lane>>4)*4 + rr;
        r8[rt][rr] = 0.125f*__expf(bcs[ri] - mb)*rqs[ri];
      }
    float c2[2];
    #pragma unroll
    for (int ct=0; ct<2; ++ct){
      int jc = jbase + ct*16 + (lane&15);
      c2[ct] = __expf(mb - bcs[jc])*rks[jc];
    }
    f32x4 s2[2][2] = {};
    #pragma unroll
    for (int s=0; s<2; ++s)
      #pragma unroll
      for (int ct=0; ct<2; ++ct){
        bf16x8 kf = *(const bf16x8*)&qkvg[(chunkbase + jbase + ct*16 + (lane&15))*4096
                                          + 1024 + h*HD + s*32 + (lane>>4)*8];
        #pragma unroll
        for (int rt=0; rt<2; ++rt)
          s2[rt][ct] = MFMA16(qf[rt][s], kf, s2[rt][ct]);
      }
    bool dia = (hb == w);
    #pragma unroll
    for (int rt=0; rt<2; ++rt)
      #pragma unroll
      for (int ct=0; ct<2; ++ct)
        #pragma unroll
        for (int rr=0; rr<4; ++rr){
          int pi = rt*16 + (lane>>4)*4 + rr;
          int pj = ct*16 + (lane&15);
          float pv = s2[rt][ct][rr] * r8[rt][rr] * c2[ct];
          if (dia && (jbase + pj) > (wrow + pi)) pv = 0.f;
          ps[w*1024 + pi*32 + (((pj>>3) ^ ((pi>>2)&3))<<3) + (pj&7)] = f2bf(pv);
        }
    bf16x8 vf[4];
    #pragma unroll
    for (int et=0; et<4; ++et){
      int e = et*16 + (lane&15);
      int jj = jbase + (lane>>4)*8;
      vf[et] = *(const bf16x8*)&vt[(e<<8) + (((jj>>3) ^ (e&7))<<3)];
    }
    bf16x8 pf[2];
    #pragma unroll
    for (int rt=0; rt<2; ++rt){
      int i = rt*16 + (lane&15);
      pf[rt] = *(const bf16x8*)&ps[w*1024 + i*32 + (((lane>>4) ^ ((i>>2)&3))<<3)];
    }
    #pragma unroll
    for (int rt=0; rt<2; ++rt)
      #pragma unroll
      for (int et=0; et<4; ++et)
        o_[rt][et] = MFMA16(pf[rt], vf[et], o_[rt][et]);
  }
  // epilogue: per-row rmsnorm (d=64), silu(g), coalesced store
  float rms8[2][4];
  #pragma unroll
  for (int rt=0; rt<2; ++rt)
    #pragma unroll
    for (int rr=0; rr<4; ++rr){
      float ssq = 0.f;
      #pragma unroll
      for (int et=0; et<4; ++et){ float xx = o_[rt][et][rr]; ssq += xx*xx; }
      ssq += __shfl_xor(ssq,1); ssq += __shfl_xor(ssq,2);
      ssq += __shfl_xor(ssq,4); ssq += __shfl_xor(ssq,8);
      rms8[rt][rr] = rsqrtf(ssq*(1.f/64.f)+1e-6f);
    }
  #pragma unroll
  for (int eh=0; eh<2; ++eh){
    #pragma unroll
    for (int rt=0; rt<2; ++rt)
      #pragma unroll
      for (int e2=0; e2<2; ++e2){
        int et = eh*2 + e2;
        #pragma unroll
        for (int rr=0; rr<4; ++rr){
          int pi = rt*16 + (lane>>4)*4 + rr;
          int pj = e2*16 + (lane&15);
          ps[w*1024 + pi*32 + (((pj>>3) ^ ((pi>>2)&3))<<3) + (pj&7)] =
            f2bf(o_[rt][et][rr]*rms8[rt][rr]);
        }
      }
    int i2 = lane&31, e16 = (lane>>5)*16;
    int gr0 = e16>>3;
    int f = (i2>>2)&3;
    short8 ov0 = *(const short8*)&ps[w*1024 + i2*32 + ((gr0^f)<<3)];
    short8 ov1 = *(const short8*)&ps[w*1024 + i2*32 + (((gr0+1)^f)<<3)];
    size_t rowg = chunkbase + wrow + i2;
    short8 gv0 = *(const short8*)&qkvg[rowg*4096 + 3072 + h*HD + eh*32 + e16];
    short8 gv1 = *(const short8*)&qkvg[rowg*4096 + 3072 + h*HD + eh*32 + e16 + 8];
    ushort_t outv[16];
    #pragma unroll
    for (int k=0;k<8;++k){
      float gf = bf2f((ushort_t)gv0[k]);
      float sg = gf/(1.f+__expf(-gf));
      outv[k] = f2bf(bf2f((ushort_t)ov0[k])*sg);
    }
    #pragma unroll
    for (int k=0;k<8;++k){
      float gf = bf2f((ushort_t)gv1[k]);
      float sg = gf/(1.f+__expf(-gf));
      outv[8+k] = f2bf(bf2f((ushort_t)ov1[k])*sg);
    }
    ushort_t* op = &oact[rowg*DIM + h*HD + eh*32 + e16];
    *(short8*)&op[0] = *(short8*)&outv[0];
    *(short8*)&op[8] = *(short8*)&outv[8];
  }
}

// ---------------- launch ----------------
extern "C" void kernel_launch(void* const* d_in, const int* in_sizes, int n_in,
                              void* d_out, int out_size, void* d_ws, size_t ws_size,
                              hipStream_t stream){
  const float* x  = (const float*)d_in[0];
  const float* Wq = (const float*)d_in[1];
  const float* Wk = (const float*)d_in[2];
  const float* Wv = (const float*)d_in[3];
  const float* Wg = (const float*)d_in[4];
  const float* Wgt= (const float*)d_in[5];
  const float* Wo = (const float*)d_in[6];
  float* out = (float*)d_out;

  char* p = (char*)d_ws;
  ushort_t* xbf  = (ushort_t*)p; p += (size_t)ROWS*DIM*2;
  ushort_t* wcat = (ushort_t*)p; p += (size_t)4*DIM*DIM*2;
  ushort_t* wot  = (ushort_t*)p; p += (size_t)DIM*DIM*2;
  ushort_t* qkvg = (ushort_t*)p; p += (size_t)ROWS*4096*2;
  float* gtb = (float*)p; p += (size_t)32*T_SEQ*4;
  float* Bb  = (float*)p; p += 1024*4;
  ushort_t* kvb = (ushort_t*)p; p += (size_t)1024*4096*2;
  ushort_t* Sb = (ushort_t*)p; p += (size_t)1024*4096*2;
  ushort_t* oact = (ushort_t*)p; p += (size_t)ROWS*DIM*2;
  float* ssqp = (float*)p; p += (size_t)48*ROWS*4;
  float* rmsb = (float*)p; p += (size_t)3*ROWS*4;
  if ((size_t)(p - (char*)d_ws) > ws_size) return;

  gt_ker<<<ROWS,256,0,stream>>>(x, Wgt, gtb, xbf);
  transpose_all<<<dim3(16,16,5),256,0,stream>>>(Wq, Wk, Wv, Wg, Wo, wcat, wot);
  gemm_bt<1><<<dim3(ROWS/128, 4096/128), 256, 0, stream>>>(xbf, wcat, qkvg, ROWS, 4096, DIM, ssqp);
  rms_combine<<<(3*ROWS)/256,256,0,stream>>>(ssqp, rmsb);
  attn_p1<<<1024,512,0,stream>>>(qkvg, gtb, rmsb, Bb, kvb);
  scan_ker<<<512,256,0,stream>>>(kvb, Bb, Sb);
  attn_p3<<<1024,512,0,stream>>>(qkvg, gtb, rmsb, Sb, oact);
  gemm_bt<0><<<dim3(ROWS/128, 1024/128), 256, 0, stream>>>(oact, wot, out, ROWS, 1024, DIM, nullptr);
}